// Round 1
// baseline (1868.271 us; speedup 1.0000x reference)
//
#include <hip/hip_runtime.h>
#include <math.h>

#define NB 128
#define SEQ 17
#define DM 192
#define DI 384
#define DSN 16
#define DRK 12
#define DEPTH 12
#define ROW (SEQ*DM)   // 3264

struct MambaW {
  const float* norm_w;
  const float* in_proj;
  const float* conv_w;
  const float* conv_b;
  const float* x_proj;
  const float* dt_w;
  const float* dt_b;
  const float* A_log;
  const float* D;
  const float* out_proj;
};

__device__ __forceinline__ float dot4(float4 a, float4 b) {
  return a.x*b.x + a.y*b.y + a.z*b.z + a.w*b.w;
}

// ---------------------------------------------------------------------------
// Patch embed (both variants): grid 256 = (bg 0..15) x (p 0..15), block 192.
// Each block: 8 batches, one patch position p, all 192 output channels.
// t-variant: t[b][p][d] = sum_{c,kh,kw} x[b][c][p*14+kh][kw] * w[d][c][kh][kw]
// f-variant: f[b][p][d] = sum_{c,kh}    x[b][c][kh][p]      * w[d][c][kh]
// plus bias + pos; row 16 = tok + pos[16].
// ---------------------------------------------------------------------------
__global__ __launch_bounds__(192, 1) void embed_kernel(
    const float* __restrict__ x, const float* __restrict__ w,
    const float* __restrict__ bias, const float* __restrict__ tok,
    const float* __restrict__ pos, float* __restrict__ xb, int is_f)
{
  const int t = threadIdx.x;
  const int p = blockIdx.x & 15;
  const int bg = blockIdx.x >> 4;
  __shared__ alignas(16) float xs[8*1792];

  for (int idx = t; idx < 8*1792; idx += 192) {
    int bb = idx / 1792;
    int r = idx - bb*1792;          // r = c*224 + (kh*16+kw) [t] or c*224+kh [f]
    int b = bg*8 + bb;
    if (!is_f) {
      int c = r / 224;
      int rr = r - c*224;
      xs[idx] = x[((size_t)(b*8 + c)*224 + p*14)*16 + rr];
    } else {
      xs[idx] = x[((size_t)b*1792 + r)*16 + p];
    }
  }
  __syncthreads();

  float acc[8];
#pragma unroll
  for (int i = 0; i < 8; ++i) acc[i] = 0.f;
  const float4* wr = (const float4*)w + t*448;
  const float4* xv = (const float4*)xs;
  for (int k4 = 0; k4 < 448; ++k4) {
    float4 w4 = wr[k4];
#pragma unroll
    for (int bb = 0; bb < 8; ++bb) acc[bb] += dot4(xv[bb*448 + k4], w4);
  }
  float add = bias[t] + pos[p*DM + t];
#pragma unroll
  for (int bb = 0; bb < 8; ++bb)
    xb[(size_t)(bg*8 + bb)*ROW + p*DM + t] = acc[bb] + add;
  if (p == 0) {
    float tv = tok[t] + pos[16*DM + t];
#pragma unroll
    for (int bb = 0; bb < 8; ++bb)
      xb[(size_t)(bg*8 + bb)*ROW + 16*DM + t] = tv;
  }
}

// ---------------------------------------------------------------------------
// One fused mamba layer for one (stream, batch). grid 256, block 384.
// Thread t owns DI-channel c=t through conv/dt/scan; in_proj columns t & t+384
// (the z half lives in registers from in_proj straight to the gate).
// ---------------------------------------------------------------------------
__global__ __launch_bounds__(384, 1) void mamba_layer_kernel(
    float* __restrict__ res, float* __restrict__ xbuf,
    MambaW wt, MambaW wf, int layer, int first)
{
  const int t = threadIdx.x;
  const int s = blockIdx.x >> 7;
  const int b = blockIdx.x & 127;
  const MambaW W = s ? wf : wt;
  float* res_p = res + (size_t)(s*NB + b)*ROW;
  float* x_p   = xbuf + (size_t)(s*NB + b)*ROW;

  __shared__ alignas(16) float lds_h[ROW];          // normed input, then dead
  __shared__ alignas(16) float lds_xx[SEQ*388];     // silu(conv(xx)); later gated y
  __shared__ alignas(16) float lds_dbl[SEQ*44];     // x_proj out: [dt_in|B|C]
  __shared__ float lds_part[17*16];
  __shared__ float lds_scale[17];

  // ---- phase 0: residual update + RMSNorm -> lds_h ----
  const float* nw = W.norm_w + layer*DM;
  for (int idx = t; idx < ROW; idx += 384) {
    float v = x_p[idx];
    if (!first) v += res_p[idx];
    res_p[idx] = v;
    lds_h[idx] = v;
  }
  __syncthreads();
  if (t < 272) {
    int l = t >> 4, j = t & 15;
    float pp = 0.f;
    for (int d = j; d < DM; d += 16) { float v = lds_h[l*DM + d]; pp += v*v; }
    lds_part[t] = pp;
  }
  __syncthreads();
  if (t < 17) {
    float ss = 0.f;
#pragma unroll
    for (int j = 0; j < 16; ++j) ss += lds_part[(t << 4) + j];
    lds_scale[t] = rsqrtf(ss * (1.0f/192.0f) + 1e-5f);
  }
  __syncthreads();
  for (int idx = t; idx < ROW; idx += 384) {
    int l = idx / DM;
    int d = idx - l*DM;
    lds_h[idx] = lds_h[idx] * lds_scale[l] * nw[d];
  }
  __syncthreads();

  // ---- phase 1: in_proj. xz[l][o] = sum_k h[l][k]*Wip[o][k]; o = t (xx), t+384 (z) ----
  float accA[17], accZ[17];
#pragma unroll
  for (int l = 0; l < 17; ++l) { accA[l] = 0.f; accZ[l] = 0.f; }
  {
    const float4* ipv = (const float4*)(W.in_proj + (size_t)layer*768*DM);
    const float4* hv4 = (const float4*)lds_h;
    const float4* wa = ipv + t*48;
    const float4* wz = ipv + (t + 384)*48;
    for (int k4 = 0; k4 < 48; ++k4) {
      float4 A4 = wa[k4];
      float4 Z4 = wz[k4];
#pragma unroll
      for (int l = 0; l < 17; ++l) {
        float4 h4 = hv4[l*48 + k4];   // wave-uniform broadcast
        accA[l] += dot4(h4, A4);
        accZ[l] += dot4(h4, Z4);
      }
    }
  }

  // ---- phase 2: causal conv (kernel 4) + SiLU, channel c = t, all in regs ----
  {
    const float4 cw = ((const float4*)(W.conv_w + (size_t)layer*DI*4))[t];
    const float cb = W.conv_b[layer*DI + t];
#pragma unroll
    for (int l = 0; l < 17; ++l) {
      float v = cb + accA[l]*cw.w;
      if (l >= 1) v += accA[l-1]*cw.z;
      if (l >= 2) v += accA[l-2]*cw.y;
      if (l >= 3) v += accA[l-3]*cw.x;
      v = v / (1.f + __expf(-v));
      lds_xx[l*388 + t] = v;
    }
  }
  __syncthreads();

  // ---- phase 3: x_proj -> dbl[l][j], j<44. Row reuse served by L1. ----
  {
    const float* XP = W.x_proj + (size_t)layer*44*DI;
#pragma unroll
    for (int rep = 0; rep < 2; ++rep) {
      int idx = t + rep*384;
      if (idx < 748) {
        int l = idx / 44;
        int j = idx - l*44;
        const float4* wr = (const float4*)(XP + j*DI);
        const float4* xr = (const float4*)lds_xx + l*97;
        float acc = 0.f;
        for (int k4 = 0; k4 < 96; ++k4) acc += dot4(xr[k4], wr[k4]);
        lds_dbl[idx] = acc;
      }
    }
  }
  __syncthreads();

  // ---- phase 4: dt = softplus(dbl[:,:12] @ dtw[c] + dtb[c]) in registers ----
  float dtv[17];
  {
    const float* wr = W.dt_w + (size_t)layer*DI*DRK + t*DRK;
    float w0[12];
#pragma unroll
    for (int r = 0; r < 12; ++r) w0[r] = wr[r];
    const float dtb = W.dt_b[layer*DI + t];
#pragma unroll
    for (int l = 0; l < 17; ++l) {
      float a = dtb;
#pragma unroll
      for (int r = 0; r < 12; ++r) a += lds_dbl[l*44 + r] * w0[r];
      dtv[l] = (a > 20.f) ? a : log1pf(__expf(a));
    }
  }

  // ---- phase 5: selective scan, state in registers; write gated y over xx ----
  {
    const float4* alr = (const float4*)(W.A_log + (size_t)layer*DI*DSN) + t*4;
    float Av[16];
#pragma unroll
    for (int q = 0; q < 4; ++q) {
      float4 a4 = alr[q];
      Av[q*4+0] = -__expf(a4.x);
      Av[q*4+1] = -__expf(a4.y);
      Av[q*4+2] = -__expf(a4.z);
      Av[q*4+3] = -__expf(a4.w);
    }
    const float Dp = W.D[layer*DI + t];
    float hst[16];
#pragma unroll
    for (int n = 0; n < 16; ++n) hst[n] = 0.f;
    for (int l = 0; l < 17; ++l) {
      float dtl = dtv[l];
      float xv = lds_xx[l*388 + t];
      const float4* dbv = (const float4*)(lds_dbl + l*44 + 12);  // 16B aligned
      float4 Bq[4], Cq[4];
      Bq[0]=dbv[0]; Bq[1]=dbv[1]; Bq[2]=dbv[2]; Bq[3]=dbv[3];
      Cq[0]=dbv[4]; Cq[1]=dbv[5]; Cq[2]=dbv[6]; Cq[3]=dbv[7];
      const float* Bs = (const float*)Bq;
      const float* Cs = (const float*)Cq;
      float y = 0.f;
      float dbx = dtl * xv;
#pragma unroll
      for (int n = 0; n < 16; ++n) {
        float dA = __expf(dtl * Av[n]);
        float hn = dA*hst[n] + dbx*Bs[n];
        hst[n] = hn;
        y += hn*Cs[n];
      }
      y += Dp * xv;
      float z = accZ[l];
      y *= z / (1.f + __expf(-z));
      lds_xx[l*388 + t] = y;
    }
  }
  __syncthreads();

  // ---- phase 6: out_proj -> x_p. thread (g = t/192, d = t%192) ----
  {
    const int g = (t >= 192) ? 1 : 0;
    const int d = t - g*192;
    const float4* wrow = (const float4*)(W.out_proj + (size_t)layer*DM*DI) + d*96;
    const float4* yv = (const float4*)lds_xx;
    float acc[9];
#pragma unroll
    for (int q = 0; q < 9; ++q) acc[q] = 0.f;
    for (int k4 = 0; k4 < 96; ++k4) {
      float4 w4 = wrow[k4];
      int base = g*97 + k4;
#pragma unroll
      for (int q = 0; q < 8; ++q) acc[q] += dot4(yv[base + q*194], w4);
      if (!g) acc[8] += dot4(yv[16*97 + k4], w4);
    }
#pragma unroll
    for (int q = 0; q < 8; ++q) x_p[(g + 2*q)*DM + d] = acc[q];
    if (!g) x_p[16*DM + d] = acc[8];
  }
}

// ---------------------------------------------------------------------------
// Both cross-attentions + heads. Only query row 16 matters end-to-end.
// grid 128 (batch), block 256.
// ---------------------------------------------------------------------------
__global__ __launch_bounds__(256, 1) void attn_head_kernel(
    const float* __restrict__ xbuf,
    const float* __restrict__ w1, const float* __restrict__ b1,
    const float* __restrict__ w2, const float* __restrict__ b2,
    const float* __restrict__ c1w, const float* __restrict__ c1b,
    const float* __restrict__ c2w, const float* __restrict__ c2b,
    const float* __restrict__ p1w, const float* __restrict__ p1b,
    const float* __restrict__ p2w, const float* __restrict__ p2b,
    float* __restrict__ out)
{
  const int t = threadIdx.x;
  const int b = blockIdx.x;
  __shared__ alignas(16) float lds_f[ROW];
  __shared__ alignas(16) float lds_k[ROW];
  __shared__ alignas(16) float lds_v[ROW];
  __shared__ alignas(16) float lds_trow[DM];
  __shared__ alignas(16) float lds_q[DM];
  __shared__ alignas(16) float lds_o[DM];
  __shared__ alignas(16) float lds_t1[DM];
  __shared__ alignas(16) float lds_feat[DM];
  __shared__ alignas(16) float lds_hc[512];
  __shared__ alignas(16) float lds_hp[512];

  const float* fp = xbuf + (size_t)(NB + b)*ROW;
  const float* tp = xbuf + (size_t)b*ROW;
  for (int idx = t; idx < ROW; idx += 256) lds_f[idx] = fp[idx];
  if (t < DM) lds_trow[t] = tp[16*DM + t];
  __syncthreads();

  for (int pass = 0; pass < 2; ++pass) {
    const float* wa = pass ? w2 : w1;
    const float* ba = pass ? b2 : b1;
    if (t < DM) {
      // K (m=1) and V (m=2) projections of f
      for (int m = 1; m <= 2; ++m) {
        const float4* wr = (const float4*)(wa + m*DM*DM) + t*48;
        float acc[17];
#pragma unroll
        for (int l = 0; l < 17; ++l) acc[l] = 0.f;
        for (int k4 = 0; k4 < 48; ++k4) {
          float4 w4 = wr[k4];
#pragma unroll
          for (int l = 0; l < 17; ++l)
            acc[l] += dot4(((const float4*)lds_f)[l*48 + k4], w4);
        }
        float bv = ba[m*DM + t];
        float* dst = (m == 1) ? lds_k : lds_v;
#pragma unroll
        for (int l = 0; l < 17; ++l) dst[l*DM + t] = acc[l] + bv;
      }
      // Q projection of the single query row
      {
        const float* qsrc = pass ? lds_t1 : lds_trow;
        const float4* wr = (const float4*)wa + t*48;
        const float4* a4 = (const float4*)qsrc;
        float acc = ba[t];
        for (int k4 = 0; k4 < 48; ++k4) acc += dot4(a4[k4], wr[k4]);
        lds_q[t] = acc;
      }
    }
    __syncthreads();
    // single-query attention: thread t<192 -> (h = t/24, dd = t%24)
    if (t < DM) {
      int h = t / 24;
      float sc[17];
      float mx = -1e30f;
#pragma unroll
      for (int lk = 0; lk < 17; ++lk) {
        float s_ = 0.f;
#pragma unroll
        for (int j = 0; j < 24; ++j)
          s_ += lds_q[h*24 + j] * lds_k[lk*DM + h*24 + j];
        s_ *= 0.20412414523193154f;  // 1/sqrt(24)
        sc[lk] = s_;
        mx = fmaxf(mx, s_);
      }
      float den = 0.f;
#pragma unroll
      for (int lk = 0; lk < 17; ++lk) { float e = __expf(sc[lk] - mx); sc[lk] = e; den += e; }
      float inv = 1.f / den;
      float o = 0.f;
#pragma unroll
      for (int lk = 0; lk < 17; ++lk) o += sc[lk] * lds_v[lk*DM + t];
      lds_o[t] = o * inv;
    }
    __syncthreads();
    // output projection
    if (t < DM) {
      const float4* wr = (const float4*)(wa + 3*DM*DM) + t*48;
      const float4* a4 = (const float4*)lds_o;
      float acc = ba[3*DM + t];
      for (int k4 = 0; k4 < 48; ++k4) acc += dot4(a4[k4], wr[k4]);
      if (pass == 0) lds_t1[t] = acc;
      else lds_feat[t] = acc + lds_trow[t];   // fusion = t + attn2_out
    }
    __syncthreads();
  }

  // heads
  for (int u = t; u < 512; u += 256) {
    const float4* wc = (const float4*)c1w + u*48;
    const float4* wp = (const float4*)p1w + u*48;
    const float4* fv = (const float4*)lds_feat;
    float a1 = c1b[u], a2 = p1b[u];
    for (int k4 = 0; k4 < 48; ++k4) {
      float4 f4 = fv[k4];
      a1 += dot4(f4, wc[k4]);
      a2 += dot4(f4, wp[k4]);
    }
    lds_hc[u] = fmaxf(a1, 0.f);
    lds_hp[u] = fmaxf(a2, 0.f);
  }
  __syncthreads();
  if (t < 10) {
    const float4* wr = (const float4*)c2w + t*128;
    float acc = c2b[t];
    for (int k4 = 0; k4 < 128; ++k4) acc += dot4(((const float4*)lds_hc)[k4], wr[k4]);
    out[b*10 + t] = acc;
  }
  if (t >= 64 && t < 67) {
    int j = t - 64;
    const float4* wr = (const float4*)p2w + j*128;
    float acc = p2b[j];
    for (int k4 = 0; k4 < 128; ++k4) acc += dot4(((const float4*)lds_hp)[k4], wr[k4]);
    out[1280 + b*3 + j] = acc;
  }
}

extern "C" void kernel_launch(void* const* d_in, const int* in_sizes, int n_in,
                              void* d_out, int out_size, void* d_ws, size_t ws_size,
                              hipStream_t stream)
{
  (void)in_sizes; (void)n_in; (void)out_size; (void)ws_size;
  const float* x    = (const float*)d_in[0];
  const float* tpw  = (const float*)d_in[1];
  const float* tpb  = (const float*)d_in[2];
  const float* fpw  = (const float*)d_in[3];
  const float* fpb  = (const float*)d_in[4];
  const float* ttok = (const float*)d_in[5];
  const float* ftok = (const float*)d_in[6];
  const float* tpos = (const float*)d_in[7];
  const float* fpos = (const float*)d_in[8];
  MambaW wt { (const float*)d_in[9],  (const float*)d_in[10], (const float*)d_in[11],
              (const float*)d_in[12], (const float*)d_in[13], (const float*)d_in[14],
              (const float*)d_in[15], (const float*)d_in[16], (const float*)d_in[17],
              (const float*)d_in[18] };
  MambaW wf { (const float*)d_in[19], (const float*)d_in[20], (const float*)d_in[21],
              (const float*)d_in[22], (const float*)d_in[23], (const float*)d_in[24],
              (const float*)d_in[25], (const float*)d_in[26], (const float*)d_in[27],
              (const float*)d_in[28] };
  const float* attw  = (const float*)d_in[29];
  const float* attb  = (const float*)d_in[30];
  const float* attw2 = (const float*)d_in[31];
  const float* attb2 = (const float*)d_in[32];
  const float* c1w = (const float*)d_in[33];
  const float* c1b = (const float*)d_in[34];
  const float* c2w = (const float*)d_in[35];
  const float* c2b = (const float*)d_in[36];
  const float* p1w = (const float*)d_in[37];
  const float* p1b = (const float*)d_in[38];
  const float* p2w = (const float*)d_in[39];
  const float* p2b = (const float*)d_in[40];

  float* ws  = (float*)d_ws;
  float* res = ws;                        // [2][128][17][192]
  float* xb  = ws + (size_t)2*NB*ROW;     // [2][128][17][192]

  embed_kernel<<<256, 192, 0, stream>>>(x, tpw, tpb, ttok, tpos, xb, 0);
  embed_kernel<<<256, 192, 0, stream>>>(x, fpw, fpb, ftok, fpos, xb + (size_t)NB*ROW, 1);
  for (int i = 0; i < DEPTH; ++i)
    mamba_layer_kernel<<<256, 384, 0, stream>>>(res, xb, wt, wf, i, i == 0 ? 1 : 0);
  attn_head_kernel<<<128, 256, 0, stream>>>(xb, attw, attb, attw2, attb2,
      c1w, c1b, c2w, c2b, p1w, p1b, p2w, p2b, (float*)d_out);
}